// Round 1
// baseline (305.958 us; speedup 1.0000x reference)
//
#include <hip/hip_runtime.h>

// RGBRenderer: out[ray][c] = sum_s w_s * rgb[ray][s][c]
//   dd_s = deltas[ray][s] * density[ray][s]
//   w_s  = exp(-cum_s) - exp(-cum_{s+1})   (telescoped, cum = exclusive cumsum)
//
// One wave per ray. FAST PATH: samples 0..127 in a single pass — lane i owns
// samples 2i, 2i+1 (float2 loads of deltas/density). For U(0,1)*U(0,1) data the
// optical depth of 128 samples is ~N(32, 2.5); P(< 13.8) ~ 1e-12, so the
// chunked fallback for samples 128..255 is correctness-only, ~never executed.
//
// Latency hiding: rgb for samples 0..63 (lanes < 32) is prefetched BEFORE the
// scan (needed by ~100% of rays; the cutoff T<1e-6 lands near sample ~55), so
// its HBM round-trip overlaps the 6-step ds_bpermute scan chain instead of
// serializing after it. Lanes >= 32 load rgb predicated on T > 1e-6 (the rest
// of the ray contributes <= 1e-6 total, 4 orders under the pass threshold).

#define N_RAYS 65536
#define N_SAMPLES 256

__global__ __launch_bounds__(256) void rgb_render_kernel(
    const float* __restrict__ rgb,      // [N_RAYS, 256, 3]
    const float* __restrict__ density,  // [N_RAYS, 256]
    const float* __restrict__ deltas,   // [N_RAYS, 256]
    float* __restrict__ out)            // [N_RAYS, 3]
{
    const int lane = threadIdx.x & 63;
    const int ray  = (int)((blockIdx.x * blockDim.x + threadIdx.x) >> 6);

    const float2* __restrict__ dl2 =
        (const float2*)(deltas + (size_t)ray * N_SAMPLES);
    const float2* __restrict__ dn2 =
        (const float2*)(density + (size_t)ray * N_SAMPLES);
    const float3* __restrict__ r3 =
        (const float3*)(rgb + (size_t)ray * (N_SAMPLES * 3));

    // ---- fast path: samples 0..127, lane i owns samples 2i, 2i+1 ----
    const float2 d = dl2[lane];
    const float2 n = dn2[lane];

    // Prefetch rgb for samples 0..63 before the scan; overlaps scan latency.
    float3 v0 = {0.f, 0.f, 0.f}, v1 = {0.f, 0.f, 0.f};
    if (lane < 32) {
        v0 = r3[2 * lane];
        v1 = r3[2 * lane + 1];
    }

    const float dd0  = d.x * n.x;
    const float dd1  = d.y * n.y;
    const float pair = dd0 + dd1;

    // wave-inclusive scan of per-lane pair sums (64 lanes)
    float x = pair;
    #pragma unroll
    for (int off = 1; off < 64; off <<= 1) {
        float y = __shfl_up(x, off, 64);
        if (lane >= off) x += y;
    }
    const float total128 = __shfl(x, 63, 64);   // uniform: depth of samples 0..127

    const float excl0 = x - pair;        // exclusive cumsum before sample 2i
    const float incl0 = excl0 + dd0;     // == exclusive before sample 2i+1
    const float incl1 = incl0 + dd1;
    const float e0 = __expf(-excl0);     // T entering sample 2i
    const float e1 = __expf(-incl0);     // T entering sample 2i+1
    const float e2 = __expf(-incl1);
    float w0 = e0 - e1;
    float w1 = e1 - e2;

    // lanes >= 32 (samples 64..127): predicated, ~10% of rays reach them
    if (lane >= 32) {
        if (e0 > 1e-6f) {
            v0 = r3[2 * lane];
            v1 = r3[2 * lane + 1];
        } else {
            w0 = 0.f;   // keep FMAs safe (v0/v1 are zero-init anyway)
            w1 = 0.f;
        }
    }

    float rr = fmaf(w0, v0.x, w1 * v1.x);
    float gg = fmaf(w0, v0.y, w1 * v1.y);
    float bb = fmaf(w0, v0.z, w1 * v1.z);

    // ---- fallback: samples 128..255 (P ~ 1e-12 per ray on this data) ----
    float run = total128;
    if (run <= 13.8f) {
        const float* dl = deltas  + (size_t)ray * N_SAMPLES;
        const float* dn = density + (size_t)ray * N_SAMPLES;
        #pragma unroll 1
        for (int c = 2; c < 4; ++c) {
            const int s = c * 64 + lane;
            float dd = dl[s] * dn[s];
            float xx = dd;
            #pragma unroll
            for (int off = 1; off < 64; off <<= 1) {
                float y = __shfl_up(xx, off, 64);
                if (lane >= off) xx += y;
            }
            const float incl = run + xx;
            const float excl = incl - dd;
            const float Ts = __expf(-excl);
            const float w  = Ts - __expf(-incl);
            if (Ts > 1e-6f) {
                float3 v = r3[s];
                rr = fmaf(w, v.x, rr);
                gg = fmaf(w, v.y, gg);
                bb = fmaf(w, v.z, bb);
            }
            run += __shfl(xx, 63, 64);
            if (run > 13.8f) break;
        }
    }

    // wave reduction of the 3 channel partials (3 independent 6-step chains)
    #pragma unroll
    for (int off = 32; off > 0; off >>= 1) {
        rr += __shfl_down(rr, off, 64);
        gg += __shfl_down(gg, off, 64);
        bb += __shfl_down(bb, off, 64);
    }

    if (lane == 0) {
        float* o = out + (size_t)ray * 3;
        o[0] = rr;
        o[1] = gg;
        o[2] = bb;
    }
}

extern "C" void kernel_launch(void* const* d_in, const int* in_sizes, int n_in,
                              void* d_out, int out_size, void* d_ws, size_t ws_size,
                              hipStream_t stream) {
    const float* rgb     = (const float*)d_in[0];
    const float* density = (const float*)d_in[1];
    const float* deltas  = (const float*)d_in[2];
    float* out = (float*)d_out;

    // one wave per ray, 4 waves per block
    dim3 block(256);
    dim3 grid(N_RAYS / 4);
    rgb_render_kernel<<<grid, block, 0, stream>>>(rgb, density, deltas, out);
}

// Round 2
// 299.988 us; speedup vs baseline: 1.0199x; 1.0199x over previous
//
#include <hip/hip_runtime.h>

// RGBRenderer: out[ray][c] = sum_s w_s * rgb[ray][s][c]
//   dd_s = deltas[ray][s] * density[ray][s]
//   w_s  = exp(-cum_s) - exp(-cum_{s+1})   (telescoped, cum = exclusive cumsum)
//
// One wave per ray, 1 sample/lane, 64-sample fast chunk.
// Traffic-minimal (R0) + latency-overlapped (R1) hybrid:
//   - deltas/density read ONLY for samples 0..63 on the fast path (~33.5 MB
//     total). With U(0,1)*U(0,1) data the chunk-0 optical depth is ~N(16,1.76),
//     so ~90% of rays terminate after chunk 0 (T < 1e-6 at ~sample 48-55).
//   - rgb for samples 0..63 is loaded UNCONDITIONALLY and issued BEFORE the
//     scan: its HBM round-trip overlaps the 6-step ds_bpermute scan chain.
//     Beyond the cutoff w ~= 0 (< 1e-6), so the unpredicated FMA is harmless
//     (+9 MB vs predicated, -1 serialized HBM trip on the common path).
//   - Chunks 1..3 are the rare (~10% / ~1% / ~0%) fallback, with predicated
//     rgb loads; early-exit when accumulated depth > 13.8 (T < 1e-6, remaining
//     contribution <= 1e-6 — 4 orders under the 1.8e-2 pass threshold).

#define N_RAYS 65536
#define N_SAMPLES 256

__global__ __launch_bounds__(256) void rgb_render_kernel(
    const float* __restrict__ rgb,      // [N_RAYS, 256, 3]
    const float* __restrict__ density,  // [N_RAYS, 256]
    const float* __restrict__ deltas,   // [N_RAYS, 256]
    float* __restrict__ out)            // [N_RAYS, 3]
{
    const int lane = threadIdx.x & 63;
    const int ray  = (int)((blockIdx.x * blockDim.x + threadIdx.x) >> 6);

    const float* __restrict__ dl = deltas  + (size_t)ray * N_SAMPLES;
    const float* __restrict__ dn = density + (size_t)ray * N_SAMPLES;
    const float3* __restrict__ r3 =
        (const float3*)(rgb + (size_t)ray * (N_SAMPLES * 3));

    // ---- fast chunk: samples 0..63, all loads issued up front ----
    const float dlv = dl[lane];
    const float dnv = dn[lane];
    const float3 v  = r3[lane];          // overlaps the scan chain below

    const float dd = dlv * dnv;

    // wave-inclusive scan of dd (64 lanes, 6 dependent steps)
    float x = dd;
    #pragma unroll
    for (int off = 1; off < 64; off <<= 1) {
        float y = __shfl_up(x, off, 64);
        if (lane >= off) x += y;
    }

    const float excl = x - dd;           // exclusive cumsum before this sample
    const float Ts = __expf(-excl);      // transmittance entering this sample
    const float w  = Ts - __expf(-x);    // >= 0; ~0 (<1e-6) past the cutoff

    float rr = w * v.x;
    float gg = w * v.y;
    float bb = w * v.z;

    float run = __shfl(x, 63, 64);       // chunk-0 total, uniform broadcast

    // ---- fallback chunks: samples 64..255 (~10% of rays enter) ----
    if (run <= 13.8f) {
        #pragma unroll 1
        for (int c = 1; c < N_SAMPLES / 64; ++c) {
            const int s = c * 64 + lane;
            const float ddf = dl[s] * dn[s];
            float xx = ddf;
            #pragma unroll
            for (int off = 1; off < 64; off <<= 1) {
                float y = __shfl_up(xx, off, 64);
                if (lane >= off) xx += y;
            }
            const float incl = run + xx;
            const float ex   = incl - ddf;
            const float T2 = __expf(-ex);
            const float w2 = T2 - __expf(-incl);
            if (T2 > 1e-6f) {            // skipped lanes contribute <= 1e-6
                float3 vf = r3[s];
                rr = fmaf(w2, vf.x, rr);
                gg = fmaf(w2, vf.y, gg);
                bb = fmaf(w2, vf.z, bb);
            }
            run += __shfl(xx, 63, 64);
            if (run > 13.8f) break;
        }
    }

    // wave reduction of the 3 channel partials (3 independent 6-step chains)
    #pragma unroll
    for (int off = 32; off > 0; off >>= 1) {
        rr += __shfl_down(rr, off, 64);
        gg += __shfl_down(gg, off, 64);
        bb += __shfl_down(bb, off, 64);
    }

    if (lane == 0) {
        float* o = out + (size_t)ray * 3;
        o[0] = rr;
        o[1] = gg;
        o[2] = bb;
    }
}

extern "C" void kernel_launch(void* const* d_in, const int* in_sizes, int n_in,
                              void* d_out, int out_size, void* d_ws, size_t ws_size,
                              hipStream_t stream) {
    const float* rgb     = (const float*)d_in[0];
    const float* density = (const float*)d_in[1];
    const float* deltas  = (const float*)d_in[2];
    float* out = (float*)d_out;

    // one wave per ray, 4 waves per block
    dim3 block(256);
    dim3 grid(N_RAYS / 4);
    rgb_render_kernel<<<grid, block, 0, stream>>>(rgb, density, deltas, out);
}